// Round 6
// baseline (847.098 us; speedup 1.0000x reference)
//
#include <hip/hip_runtime.h>

typedef unsigned int uint;
typedef unsigned short ushort;
typedef unsigned long long u64;

typedef __bf16 bf16x8 __attribute__((ext_vector_type(8)));
typedef float f32x4 __attribute__((ext_vector_type(4)));
union U8 { uint4 u4; uint w[4]; bf16x8 b; };

#define NBK 256   // LDS bins allocated (196 used)
#define CAP 16    // msgs per bin (16*8B = 128B flush)

__device__ __forceinline__ float bf2f(ushort u) {
    return __uint_as_float(((uint)u) << 16);
}
__device__ __forceinline__ float2 bfp2f(uint u) {
    float2 r;
    r.x = __uint_as_float(u << 16);
    r.y = __uint_as_float(u & 0xffff0000u);
    return r;
}
__device__ __forceinline__ ushort f2bf(float f) {
    uint u = __float_as_uint(f);
    return (ushort)((u + 0x7fffu + ((u >> 16) & 1u)) >> 16);  // RNE
}

// ---------------------------------------------------------------------------
// PRE kernel: degree counting + proj (+ folded Wo -> Vt) + cvt low halves
// ---------------------------------------------------------------------------
__global__ void pre_kernel(const float* __restrict__ W_word,
                           const float* __restrict__ Wq,
                           const float* __restrict__ Wk,
                           const float* __restrict__ Wv,
                           const float* __restrict__ Wo,
                           ushort* __restrict__ Pq, ushort* __restrict__ Pk,
                           ushort* __restrict__ Vt,
                           const float* __restrict__ W_query,
                           const float* __restrict__ W_entity,
                           ushort* __restrict__ qe0b, ushort* __restrict__ e0b,
                           const int* __restrict__ p_src,
                           const int* __restrict__ p_dst,
                           const int* __restrict__ profile_dst,
                           int* __restrict__ degc, int* __restrict__ degp,
                           int WORD, int Qn, int N, int E, int R,
                           int nc_blk, int npj_blk, int ncq_blk, int nce_blk) {
    int bid = blockIdx.x;
    int g = bid >> 3, j = bid & 7;
    if ((g & 3) == 3) {                       // count family
        int idx = (g >> 2) * 8 + j;
        if (idx >= nc_blk) return;
        int t = idx * 256 + threadIdx.x;
        if (t < E) {
            atomicAdd(&degc[p_src[t]], 1);
            atomicAdd(&degc[p_dst[t]], 1);
        }
        if (t < R) atomicAdd(&degp[profile_dst[t]], 1);
        return;
    }
    int idx = ((g >> 2) * 3 + (g & 3)) * 8 + j;
    if (idx < npj_blk) {
        int wid  = idx * 4 + (threadIdx.x >> 6);
        int lane = threadIdx.x & 63;
        if (wid >= WORD) return;
        float x = W_word[(size_t)wid * 64 + lane];
        float aq = 0.f, ak = 0.f, av = 0.f;
#pragma unroll
        for (int i = 0; i < 64; i++) {
            float xi = __shfl(x, i, 64);
            aq = fmaf(xi, Wq[i * 64 + lane], aq);
            ak = fmaf(xi, Wk[i * 64 + lane], ak);
            av = fmaf(xi, Wv[i * 64 + lane], av);
        }
        size_t o = (size_t)wid * 64 + lane;
        Pq[o] = f2bf(aq); Pk[o] = f2bf(ak);
        float vt[4] = {0.f, 0.f, 0.f, 0.f};
#pragma unroll
        for (int i = 0; i < 64; i++) {
            float vi = __shfl(av, i, 64);
            vt[i >> 4] = fmaf(vi, Wo[i * 64 + lane], vt[i >> 4]);
        }
#pragma unroll
        for (int h = 0; h < 4; h++)
            Vt[((size_t)wid * 4 + h) * 64 + lane] = f2bf(vt[h]);
    } else if (idx < npj_blk + ncq_blk) {
        int t = (idx - npj_blk) * 256 + threadIdx.x;
        if (t >= Qn * 16) return;
        int r = t >> 4, c = (t & 15) * 4;
        const float4 v = *(const float4*)(W_query + (size_t)r * 64 + c);
        ushort4 o;
        o.x = f2bf(v.x); o.y = f2bf(v.y); o.z = f2bf(v.z); o.w = f2bf(v.w);
        *(ushort4*)(qe0b + (size_t)r * 128 + c) = o;
    } else if (idx < npj_blk + ncq_blk + nce_blk) {
        int t = (idx - npj_blk - ncq_blk) * 256 + threadIdx.x;
        if (t >= N * 16) return;
        int r = t >> 4, c = (t & 15) * 4;
        const float4 v = *(const float4*)(W_entity + (size_t)r * 64 + c);
        ushort4 o;
        o.x = f2bf(v.x); o.y = f2bf(v.y); o.z = f2bf(v.z); o.w = f2bf(v.w);
        *(ushort4*)(e0b + (size_t)r * 128 + c) = o;
    }
}

// ---------------------------------------------------------------------------
// fused prefix scans for degc and degp (1024-elem chunks)
// ---------------------------------------------------------------------------
__global__ void scan_sum2(const int* __restrict__ degc,
                          const int* __restrict__ degp,
                          int* __restrict__ csum, int* __restrict__ csum2,
                          int N, int nchunk) {
    __shared__ int red[4];
    int arr = blockIdx.x >= nchunk;
    const int* deg = arr ? degp : degc;
    int* cs = arr ? csum2 : csum;
    int chunk = arr ? blockIdx.x - nchunk : blockIdx.x;
    int t = threadIdx.x;
    int base = chunk * 1024;
    int v = 0;
#pragma unroll
    for (int k = 0; k < 4; k++) {
        int idx = base + t * 4 + k;
        if (idx < N) v += deg[idx];
    }
#pragma unroll
    for (int o = 32; o; o >>= 1) v += __shfl_down(v, o, 64);
    if ((t & 63) == 0) red[t >> 6] = v;
    __syncthreads();
    if (t == 0) cs[chunk] = red[0] + red[1] + red[2] + red[3];
}

__global__ void scan_blocks2(int* __restrict__ csum, int* __restrict__ csum2,
                             int nchunk) {
    __shared__ int lds[256];
    for (int a = 0; a < 2; a++) {
        int* cs = a ? csum2 : csum;
        int t = threadIdx.x;
        int v = (t < nchunk) ? cs[t] : 0;
        lds[t] = v;
        __syncthreads();
        for (int o = 1; o < 256; o <<= 1) {
            int u = (t >= o) ? lds[t - o] : 0;
            __syncthreads();
            lds[t] += u;
            __syncthreads();
        }
        if (t < nchunk) cs[t] = lds[t] - v;  // exclusive
        __syncthreads();
    }
}

__global__ void scan_chunk2(const int* __restrict__ degc,
                            const int* __restrict__ degp,
                            const int* __restrict__ csum,
                            const int* __restrict__ csum2,
                            int* __restrict__ offs, int* __restrict__ cursor,
                            int* __restrict__ offs_r, int* __restrict__ cursor_r,
                            float* __restrict__ inv, int N, int nchunk) {
    __shared__ int lds[256];
    int arr = blockIdx.x >= nchunk;
    const int* deg = arr ? degp : degc;
    const int* cs  = arr ? csum2 : csum;
    int* of = arr ? offs_r : offs;
    int* cu = arr ? cursor_r : cursor;
    int chunk = arr ? blockIdx.x - nchunk : blockIdx.x;
    int t = threadIdx.x;
    int base = chunk * 1024 + t * 4;
    int v0 = (base + 0 < N) ? deg[base + 0] : 0;
    int v1 = (base + 1 < N) ? deg[base + 1] : 0;
    int v2 = (base + 2 < N) ? deg[base + 2] : 0;
    int v3 = (base + 3 < N) ? deg[base + 3] : 0;
    if (!arr) {
        if (base + 0 < N) inv[base + 0] = 1.0f / sqrtf((float)max(v0, 1));
        if (base + 1 < N) inv[base + 1] = 1.0f / sqrtf((float)max(v1, 1));
        if (base + 2 < N) inv[base + 2] = 1.0f / sqrtf((float)max(v2, 1));
        if (base + 3 < N) inv[base + 3] = 1.0f / sqrtf((float)max(v3, 1));
    }
    int s = v0 + v1 + v2 + v3;
    lds[t] = s;
    __syncthreads();
    for (int o = 1; o < 256; o <<= 1) {
        int u = (t >= o) ? lds[t - o] : 0;
        __syncthreads();
        lds[t] += u;
        __syncthreads();
    }
    int tb = lds[t] - s + cs[chunk];
    int vv[4] = {v0, v1, v2, v3};
#pragma unroll
    for (int k = 0; k < 4; k++) {
        int idx = base + k;
        if (idx < N) {
            of[idx] = tb; cu[idx] = tb; tb += vv[k];
            if (idx == N - 1) of[N] = tb;
        }
    }
}

// ---------------------------------------------------------------------------
// bucket meta: per-bucket (dst>>9) staging base (16-aligned), count, cursor
// ---------------------------------------------------------------------------
__global__ void bucket_meta(const int* __restrict__ offs,
                            int* __restrict__ sbase, int* __restrict__ scnt,
                            int* __restrict__ gcur, int N) {
    __shared__ int lds[256];
    int t = threadIdx.x;
    int NB = (N + 511) >> 9;
    int cnt = 0;
    if (t < NB) {
        int lo = t << 9, hi = min((t + 1) << 9, N);
        cnt = offs[hi] - offs[lo];
    }
    int pad = (cnt + 15) & ~15;
    lds[t] = pad;
    __syncthreads();
    for (int o = 1; o < 256; o <<= 1) {
        int u = (t >= o) ? lds[t - o] : 0;
        __syncthreads();
        lds[t] += u;
        __syncthreads();
    }
    if (t < NB) {
        int sb = lds[t] - pad;
        sbase[t] = sb; gcur[t] = sb; scnt[t] = cnt;
    }
}

// ---------------------------------------------------------------------------
// MFMA MHSA: one wave = TWO sequences (unchanged from R5, verified)
// ---------------------------------------------------------------------------
__device__ __forceinline__ void mhsa_pair(const ushort* __restrict__ Pq,
                                          const ushort* __restrict__ Pk,
                                          const ushort* __restrict__ Vt,
                                          const int* __restrict__ ids,
                                          int wid2, int lane, int mode,
                                          ushort* __restrict__ outb,
                                          float* __restrict__ outf) {
    const int l15 = lane & 15;
    const int gi  = lane >> 4;
    const int hs  = gi >> 1;
    const int dbase = (gi & 1) * 8;
    const int* idr = ids + (size_t)wid2 * 16;
    const bool valid = hs == (l15 >> 3);

    const int myid = idr[l15];
    int vid[8];
#pragma unroll
    for (int i = 0; i < 8; i++) vid[i] = idr[dbase + i];

    uint pk4[4][2];
    const f32x4 zero4 = {0.f, 0.f, 0.f, 0.f};
#pragma unroll
    for (int h = 0; h < 4; h++) {
        U8 a, b;
        if (valid) {
            a.u4 = *(const uint4*)(Pk + (size_t)myid * 64 + h * 16 + dbase);
            b.u4 = *(const uint4*)(Pq + (size_t)myid * 64 + h * 16 + dbase);
        } else {
            a.u4 = make_uint4(0, 0, 0, 0);
            b.u4 = make_uint4(0, 0, 0, 0);
        }
        f32x4 d = __builtin_amdgcn_mfma_f32_16x16x32_bf16(a.b, b.b, zero4, 0, 0, 0);
        float s0 = d[0] * 0.25f, s1 = d[1] * 0.25f;
        float s2 = d[2] * 0.25f, s3 = d[3] * 0.25f;
        if (!valid) { s0 = s1 = s2 = s3 = -1e30f; }
        float mx = fmaxf(fmaxf(s0, s1), fmaxf(s2, s3));
        mx = fmaxf(mx, __shfl_xor(mx, 16, 64));
        mx = fmaxf(mx, __shfl_xor(mx, 32, 64));
        float x0 = __expf(s0 - mx), x1 = __expf(s1 - mx);
        float x2 = __expf(s2 - mx), x3 = __expf(s3 - mx);
        float sm = x0 + x1 + x2 + x3;
        sm += __shfl_xor(sm, 16, 64);
        sm += __shfl_xor(sm, 32, 64);
        float f = 0.125f / sm;
        uint w0 = (uint)f2bf(x0 * f) | ((uint)f2bf(x1 * f) << 16);
        uint w1 = (uint)f2bf(x2 * f) | ((uint)f2bf(x3 * f) << 16);
        pk4[h][0] = valid ? w0 : 0u;
        pk4[h][1] = valid ? w1 : 0u;
    }

    const int srcA = l15 + (gi & 1) * 32;
    const int srcB = srcA + 16;
    uint aw[2][4];
#pragma unroll
    for (int P = 0; P < 2; P++) {
        uint r00 = (uint)__shfl((int)pk4[2 * P][0], srcA, 64);
        uint r01 = (uint)__shfl((int)pk4[2 * P][1], srcA, 64);
        uint r02 = (uint)__shfl((int)pk4[2 * P][0], srcB, 64);
        uint r03 = (uint)__shfl((int)pk4[2 * P][1], srcB, 64);
        uint r10 = (uint)__shfl((int)pk4[2 * P + 1][0], srcA, 64);
        uint r11 = (uint)__shfl((int)pk4[2 * P + 1][1], srcA, 64);
        uint r12 = (uint)__shfl((int)pk4[2 * P + 1][0], srcB, 64);
        uint r13 = (uint)__shfl((int)pk4[2 * P + 1][1], srcB, 64);
        aw[P][0] = hs ? r10 : r00;
        aw[P][1] = hs ? r11 : r01;
        aw[P][2] = hs ? r12 : r02;
        aw[P][3] = hs ? r13 : r03;
    }

    size_t vb[8];
#pragma unroll
    for (int i = 0; i < 8; i++) vb[i] = (size_t)vid[i] * 256;
#pragma unroll
    for (int t = 0; t < 4; t++) {
        const int col = t * 16 + l15;
        f32x4 acc = zero4;
#pragma unroll
        for (int P = 0; P < 2; P++) {
            const int h = 2 * P + hs;
            uint e[8];
#pragma unroll
            for (int i = 0; i < 8; i++) e[i] = Vt[vb[i] + h * 64 + col];
            U8 bv;
            bv.w[0] = e[0] | (e[1] << 16);
            bv.w[1] = e[2] | (e[3] << 16);
            bv.w[2] = e[4] | (e[5] << 16);
            bv.w[3] = e[6] | (e[7] << 16);
            U8 av_;
            av_.w[0] = aw[P][0]; av_.w[1] = aw[P][1];
            av_.w[2] = aw[P][2]; av_.w[3] = aw[P][3];
            acc = __builtin_amdgcn_mfma_f32_16x16x32_bf16(av_.b, bv.b, acc, 0, 0, 0);
        }
        float s = acc[0] + acc[1] + acc[2] + acc[3];
        s += __shfl_xor(s, 16, 64);
        if ((gi & 1) == 0) {
            int row = wid2 * 2 + hs;
            if (mode == 0)      outb[(size_t)row * 128 + 64 + col] = f2bf(s);
            else if (mode == 1) outb[(size_t)row * 64 + col] = f2bf(s);
            else                outf[(size_t)row * 64 + col] = s;
        }
    }
}

// ---------------------------------------------------------------------------
// pass1: LDS-binned staging of conv messages (bucket = target >> 9).
// Payload u64 = qid(17b, 0x1FFFF=reverse) << 34 | other << 17 | target.
// Full bins flush as 128B-aligned contiguous runs -> ~1x write amp.
// ---------------------------------------------------------------------------
__device__ void pass1_block(const int* __restrict__ p_src,
                            const int* __restrict__ p_dst,
                            const int* __restrict__ p_qid,
                            int* __restrict__ gcur, u64* __restrict__ gstage,
                            int E, int p, int np1,
                            int* bin_cnt, u64 (*bin_slot)[CAP]) {
    int tid = threadIdx.x;
    for (int i = tid; i < NBK; i += 256) bin_cnt[i] = 0;
    __syncthreads();
    int nch = (E + 255) >> 8;
    for (int c = p; c < nch; c += np1) {
        int e = c * 256 + tid;
        u64 pend[2]; int pb[2]; int act = 0;
        if (e < E) {
            int s = p_src[e], d = p_dst[e], q = p_qid[e];
            pend[0] = ((u64)(uint)q << 34) | ((u64)(uint)s << 17) | (uint)d;
            pb[0] = d >> 9;
            pend[1] = (0x1FFFFULL << 34) | ((u64)(uint)d << 17) | (uint)s;
            pb[1] = s >> 9;
            act = 3;
        }
        for (int iter = 0; iter < 64; iter++) {
#pragma unroll
            for (int k = 0; k < 2; k++) {
                if (act >> k & 1) {
                    int pos = atomicAdd(&bin_cnt[pb[k]], 1);
                    if (pos < CAP) { bin_slot[pb[k]][pos] = pend[k]; act &= ~(1 << k); }
                }
            }
            int rem = __syncthreads_count(act);
            if (rem == 0) break;
            if (tid < NBK) {
                int c2 = bin_cnt[tid];
                if (c2 >= CAP) {
                    int base = atomicAdd(&gcur[tid], CAP);
                    u64* dst = gstage + base;
#pragma unroll
                    for (int i = 0; i < CAP; i++) dst[i] = bin_slot[tid][i];
                    bin_cnt[tid] = 0;
                }
            }
            __syncthreads();
        }
        if (act) {  // safety spill (bounded-iteration fallback)
#pragma unroll
            for (int k = 0; k < 2; k++) {
                if (act >> k & 1) {
                    int pos = atomicAdd(&gcur[pb[k]], 1);
                    gstage[pos] = pend[k];
                }
            }
        }
    }
    __syncthreads();
    if (tid < NBK) {  // drain partial bins
        int c2 = min(bin_cnt[tid], CAP);
        if (c2 > 0) {
            int base = atomicAdd(&gcur[tid], c2);
            for (int i = 0; i < c2; i++) gstage[base + i] = bin_slot[tid][i];
        }
    }
}

// ---------------------------------------------------------------------------
// MEGA: mhsa x3 (15/16 of stripes) + {pass1, scatter_rev} (1/16)
// ---------------------------------------------------------------------------
__global__ void mega_kernel(const ushort* __restrict__ Pq,
                            const ushort* __restrict__ Pk,
                            const ushort* __restrict__ Vt,
                            const int* __restrict__ query_word_ids,
                            const int* __restrict__ review_word_ids,
                            const int* __restrict__ query_words,
                            ushort* __restrict__ qe0b,
                            ushort* __restrict__ hrev,
                            float* __restrict__ qb,
                            const int* __restrict__ p_src,
                            const int* __restrict__ p_dst,
                            const int* __restrict__ p_qid,
                            const int* __restrict__ profile_dst,
                            int* __restrict__ gcur, u64* __restrict__ gstage,
                            int* __restrict__ cursor_r, int* __restrict__ rmsg,
                            int Qn, int R, int B, int E,
                            int nr_blk, int nq_blk, int nb_blk,
                            int np1, int nv_blk) {
    __shared__ int bin_cnt[NBK];
    __shared__ u64 bin_slot[NBK][CAP];
    int bid = blockIdx.x;
    int g = bid >> 3, j = bid & 7;
    if ((g & 15) == 15) {                     // scatter family
        int idx = (g >> 4) * 8 + j;
        if (idx < np1) {
            pass1_block(p_src, p_dst, p_qid, gcur, gstage, E, idx, np1,
                        bin_cnt, bin_slot);
        } else if (idx < np1 + nv_blk) {
            int r = (idx - np1) * 256 + threadIdx.x;
            if (r >= R) return;
            rmsg[atomicAdd(&cursor_r[profile_dst[r]], 1)] = r;
        }
        return;
    }
    int idx = ((g >> 4) * 15 + (g & 15)) * 8 + j;
    int lane = threadIdx.x & 63;
    int w = threadIdx.x >> 6;
    if (idx < nr_blk) {
        int wid2 = idx * 4 + w;
        if (wid2 < (R >> 1))
            mhsa_pair(Pq, Pk, Vt, review_word_ids, wid2, lane, 1, hrev, nullptr);
    } else if (idx < nr_blk + nq_blk) {
        int wid2 = (idx - nr_blk) * 4 + w;
        if (wid2 < (Qn >> 1))
            mhsa_pair(Pq, Pk, Vt, query_word_ids, wid2, lane, 0, qe0b, nullptr);
    } else if (idx < nr_blk + nq_blk + nb_blk) {
        int wid2 = (idx - nr_blk - nq_blk) * 4 + w;
        if (wid2 < (B >> 1))
            mhsa_pair(Pq, Pk, Vt, query_words, wid2, lane, 2, nullptr, qb);
    }
}

// ---------------------------------------------------------------------------
// POST: pass2 (bucket-staged -> final node-ordered msg) + entity_gather
// ---------------------------------------------------------------------------
__global__ void post_kernel(const u64* __restrict__ gstage,
                            const int* __restrict__ sbase,
                            const int* __restrict__ scnt,
                            int* __restrict__ cursor, int2* __restrict__ msg,
                            const ushort* __restrict__ hrev,
                            const int* __restrict__ offs_r,
                            const int* __restrict__ rmsg,
                            ushort* __restrict__ e0b, int N, int np2_blk) {
    int bid = blockIdx.x;
    if (bid < np2_blk) {
        int b = bid >> 4, sl = bid & 15;
        int cnt = scnt[b], sb = sbase[b];
        int per = (cnt + 15) >> 4;
        int lo = sl * per, hi = min(lo + per, cnt);
        for (int i = lo + threadIdx.x; i < hi; i += 256) {
            u64 v = gstage[sb + i];
            int target = (int)(v & 0x1FFFF);
            int other  = (int)((v >> 17) & 0x1FFFF);
            int qid    = (int)((v >> 34) & 0x1FFFF);
            int slot = atomicAdd(&cursor[target], 1);
            msg[slot] = make_int2(other, qid == 0x1FFFF ? -1 : qid);
        }
        return;
    }
    // entity_gather family
    int idx = bid - np2_blk;
    int g = (idx * 256 + threadIdx.x) >> 4;
    int c = (threadIdx.x & 15) * 4;
    if (g >= N) return;
    int beg = offs_r[g], end = offs_r[g + 1];
    float a0 = 0.f, a1 = 0.f, a2 = 0.f, a3 = 0.f;
    for (int m = beg; m < end; m++) {
        int r = rmsg[m];
        ushort4 v = *(const ushort4*)(hrev + (size_t)r * 64 + c);
        a0 += bf2f(v.x); a1 += bf2f(v.y); a2 += bf2f(v.z); a3 += bf2f(v.w);
    }
    float s = 1.0f / (float)max(end - beg, 1);
    ushort4 o;
    o.x = f2bf(a0 * s); o.y = f2bf(a1 * s); o.z = f2bf(a2 * s); o.w = f2bf(a3 * s);
    *(ushort4*)(e0b + (size_t)g * 128 + 64 + c) = o;
}

// ---------------------------------------------------------------------------
// CSR conv gather (bf16 inputs, f32 accum): 16 lanes/node, 8 cols/lane
// ---------------------------------------------------------------------------
__global__ void gather_conv(const ushort* __restrict__ e0b,
                            const ushort* __restrict__ qe0b,
                            const float* __restrict__ inv,
                            const int* __restrict__ offs,
                            const int2* __restrict__ msg,
                            float* __restrict__ agg, int N) {
    int g = (blockIdx.x * blockDim.x + threadIdx.x) >> 4;
    int c = (threadIdx.x & 15) * 8;
    if (g >= N) return;
    int beg = offs[g], end = offs[g + 1];
    float a0 = 0.f, a1 = 0.f, a2 = 0.f, a3 = 0.f;
    float a4 = 0.f, a5 = 0.f, a6 = 0.f, a7 = 0.f;
    for (int m = beg; m < end; m++) {
        int2 mm = msg[m];
        float w = inv[mm.x];
        const uint4 ev = *(const uint4*)(e0b + (size_t)mm.x * 128 + c);
        if (mm.y >= 0) {
            const uint4 qv = *(const uint4*)(qe0b + (size_t)mm.y * 128 + c);
            float2 e, q;
            e = bfp2f(ev.x); q = bfp2f(qv.x); a0 += fmaf(q.x, w, e.x); a1 += fmaf(q.y, w, e.y);
            e = bfp2f(ev.y); q = bfp2f(qv.y); a2 += fmaf(q.x, w, e.x); a3 += fmaf(q.y, w, e.y);
            e = bfp2f(ev.z); q = bfp2f(qv.z); a4 += fmaf(q.x, w, e.x); a5 += fmaf(q.y, w, e.y);
            e = bfp2f(ev.w); q = bfp2f(qv.w); a6 += fmaf(q.x, w, e.x); a7 += fmaf(q.y, w, e.y);
        } else {
            float2 e;
            e = bfp2f(ev.x); a0 = fmaf(e.x, w, a0); a1 = fmaf(e.y, w, a1);
            e = bfp2f(ev.y); a2 = fmaf(e.x, w, a2); a3 = fmaf(e.y, w, a3);
            e = bfp2f(ev.z); a4 = fmaf(e.x, w, a4); a5 = fmaf(e.y, w, a5);
            e = bfp2f(ev.w); a6 = fmaf(e.x, w, a6); a7 = fmaf(e.y, w, a7);
        }
    }
    float4 r0; r0.x = a0; r0.y = a1; r0.z = a2; r0.w = a3;
    float4 r1; r1.x = a4; r1.y = a5; r1.z = a6; r1.w = a7;
    float* dst = agg + (size_t)g * 128 + c;
    *(float4*)dst = r0;
    *(float4*)(dst + 4) = r1;
}

// ---------------------------------------------------------------------------
// final: e(n,c) = 0.5*(e0b + agg*inv); 3 output blocks
// ---------------------------------------------------------------------------
__global__ void out_kernel(const ushort* __restrict__ e0b,
                           const float* __restrict__ agg,
                           const float* __restrict__ inv,
                           const float* __restrict__ qb,
                           const int* __restrict__ users,
                           const int* __restrict__ items,
                           const int* __restrict__ negs,
                           float* __restrict__ out, int B) {
    int t = blockIdx.x * blockDim.x + threadIdx.x;
    if (t >= B * 128) return;
    int b = t >> 7, c = t & 127;
    int u = users[b], it = items[b], ng = negs[b];
    size_t ou = (size_t)u * 128 + c, oi = (size_t)it * 128 + c, on = (size_t)ng * 128 + c;
    float eu = 0.5f * fmaf(agg[ou], inv[u], bf2f(e0b[ou]));
    float ei = 0.5f * fmaf(agg[oi], inv[it], bf2f(e0b[oi]));
    float en = 0.5f * fmaf(agg[on], inv[ng], bf2f(e0b[on]));
    float q = (c >= 64) ? qb[(size_t)b * 64 + (c - 64)] : 0.0f;
    out[t] = eu + q;
    out[(size_t)B * 128 + t] = ei;
    out[(size_t)B * 256 + t] = en;
}

// ---------------------------------------------------------------------------
extern "C" void kernel_launch(void* const* d_in, const int* in_sizes, int n_in,
                              void* d_out, int out_size, void* d_ws, size_t ws_size,
                              hipStream_t stream) {
    const float* W_word   = (const float*)d_in[0];
    const float* W_query  = (const float*)d_in[1];
    const float* W_entity = (const float*)d_in[2];
    const float* Wq       = (const float*)d_in[3];
    const float* Wk       = (const float*)d_in[4];
    const float* Wv       = (const float*)d_in[5];
    const float* Wo       = (const float*)d_in[6];
    const int* query_word_ids  = (const int*)d_in[7];
    const int* review_word_ids = (const int*)d_in[8];
    const int* profile_dst     = (const int*)d_in[9];
    const int* p_src  = (const int*)d_in[10];
    const int* p_dst  = (const int*)d_in[11];
    const int* p_qid  = (const int*)d_in[12];
    const int* users  = (const int*)d_in[13];
    const int* items  = (const int*)d_in[14];
    const int* negs   = (const int*)d_in[15];
    const int* query_words = (const int*)d_in[16];

    const int WORD = in_sizes[0] / 64;   // 50000
    const int Qn   = in_sizes[1] / 64;   // 50000
    const int N    = in_sizes[2] / 64;   // 100000
    const int R    = in_sizes[8] / 8;    // 100000
    const int E    = in_sizes[10];       // 2000000
    const int B    = in_sizes[13];       // 1024

    ushort* e0b  = (ushort*)d_ws;                       // [N,128] bf16
    ushort* qe0b = e0b + (size_t)N * 128;               // [Qn,128] bf16
    ushort* Pq   = qe0b + (size_t)Qn * 128;             // [WORD,64] bf16
    ushort* Pk   = Pq + (size_t)WORD * 64;              // [WORD,64] bf16
    ushort* Vt   = Pk + (size_t)WORD * 64;              // [WORD,4,64] bf16
    ushort* hrev = Vt + (size_t)WORD * 256;             // [R,64] bf16
    float*  agg  = (float*)Pq;                          // aliases ^ (post-POST)
    float*  qb   = (float*)(hrev + (size_t)R * 64);     // [B,64] f32
    float*  inv  = qb + (size_t)B * 64;                 // [N]
    int* degc     = (int*)(inv + N);                    // [N]
    int* degp     = degc + N;                           // [N]
    int* offs     = degp + N;                           // [N+2]
    int* cursor   = offs + N + 2;                       // [N]
    int* offs_r   = cursor + N;                         // [N+2]
    int* cursor_r = offs_r + N + 2;                     // [N]
    int* csum     = cursor_r + N;                       // [256]
    int* csum2    = csum + 256;                         // [256]
    int* sbase    = csum2 + 256;                        // [256]
    int* scnt     = sbase + 256;                        // [256]
    int* gcur     = scnt + 256;                         // [256]
    int* rmsg     = gcur + 256;                         // [R]
    int2* msg     = (int2*)(rmsg + R);                  // [2E] 8B
    u64* gstage   = (u64*)(msg + 2 * (size_t)E);        // [2E+4096] 8B

    const int nchunk = (N + 1023) / 1024;               // 98
    const int NP1 = 512;                                // pass1 persistent blocks

    hipMemsetAsync(degc, 0, 2 * (size_t)N * sizeof(int), stream);

    // PRE: count + proj(+Vt) + cvt fused
    {
        int nc_blk  = (E + 255) / 256;
        int npj_blk = (WORD + 3) / 4;
        int ncq_blk = (Qn * 16 + 255) / 256;
        int nce_blk = (N * 16 + 255) / 256;
        int mh_fam  = npj_blk + ncq_blk + nce_blk;
        int T = max(4 * nc_blk, (mh_fam * 4 + 2) / 3);
        T = ((T + 31) / 32) * 32;
        pre_kernel<<<T, 256, 0, stream>>>(W_word, Wq, Wk, Wv, Wo, Pq, Pk, Vt,
                                          W_query, W_entity, qe0b, e0b,
                                          p_src, p_dst, profile_dst, degc, degp,
                                          WORD, Qn, N, E, R,
                                          nc_blk, npj_blk, ncq_blk, nce_blk);
    }

    // fused scans + bucket meta
    scan_sum2<<<2 * nchunk, 256, 0, stream>>>(degc, degp, csum, csum2, N, nchunk);
    scan_blocks2<<<1, 256, 0, stream>>>(csum, csum2, nchunk);
    scan_chunk2<<<2 * nchunk, 256, 0, stream>>>(degc, degp, csum, csum2,
                                                offs, cursor, offs_r, cursor_r,
                                                inv, N, nchunk);
    bucket_meta<<<1, 256, 0, stream>>>(offs, sbase, scnt, gcur, N);

    // MEGA: MFMA-mhsa x3 + {pass1 binning, scatter_rev}
    {
        int nr_blk = (R / 2 + 3) / 4;
        int nq_blk = (Qn / 2 + 3) / 4;
        int nb_blk = (B / 2 + 3) / 4;
        int nv_blk = (R + 255) / 256;
        int mh = nr_blk + nq_blk + nb_blk;
        int sc = NP1 + nv_blk;
        int G = max((mh + 119) / 120, (sc + 7) / 8);
        int T = G * 128;
        mega_kernel<<<T, 256, 0, stream>>>(Pq, Pk, Vt,
                                           query_word_ids, review_word_ids, query_words,
                                           qe0b, hrev, qb,
                                           p_src, p_dst, p_qid, profile_dst,
                                           gcur, gstage, cursor_r, rmsg,
                                           Qn, R, B, E,
                                           nr_blk, nq_blk, nb_blk, NP1, nv_blk);
    }

    // POST: pass2 re-scatter (L2-local windows) + entity_gather
    {
        int NB = (N + 511) >> 9;
        int np2_blk = NB * 16;
        int nent_blk = (N * 16 + 255) / 256;
        post_kernel<<<np2_blk + nent_blk, 256, 0, stream>>>(gstage, sbase, scnt,
                                                            cursor, msg,
                                                            hrev, offs_r, rmsg,
                                                            e0b, N, np2_blk);
    }

    // conv gather (agg aliases dead Pq/Pk/Vt/hrev)
    gather_conv<<<(N * 16 + 255) / 256, 256, 0, stream>>>(e0b, qe0b, inv, offs, msg, agg, N);

    // outputs
    out_kernel<<<(B * 128 + 255) / 256, 256, 0, stream>>>(e0b, agg, inv, qb, users, items, negs, (float*)d_out, B);
}

// Round 7
// 509.868 us; speedup vs baseline: 1.6614x; 1.6614x over previous
//
#include <hip/hip_runtime.h>

typedef unsigned int uint;
typedef unsigned short ushort;

typedef __bf16 bf16x8 __attribute__((ext_vector_type(8)));
typedef float f32x4 __attribute__((ext_vector_type(4)));
union U8 { uint4 u4; uint w[4]; bf16x8 b; };

__device__ __forceinline__ float bf2f(ushort u) {
    return __uint_as_float(((uint)u) << 16);
}
__device__ __forceinline__ float2 bfp2f(uint u) {
    float2 r;
    r.x = __uint_as_float(u << 16);
    r.y = __uint_as_float(u & 0xffff0000u);
    return r;
}
__device__ __forceinline__ ushort f2bf(float f) {
    uint u = __float_as_uint(f);
    return (ushort)((u + 0x7fffu + ((u >> 16) & 1u)) >> 16);  // RNE
}

// ---------------------------------------------------------------------------
// mark output nodes: dedupe via CAS, assign compact ids
// ---------------------------------------------------------------------------
__global__ void mark_kernel(const int* __restrict__ users,
                            const int* __restrict__ items,
                            const int* __restrict__ negs,
                            int* __restrict__ mapid, int* __restrict__ mcnt,
                            int B) {
    int t = blockIdx.x * blockDim.x + threadIdx.x;
    if (t >= 3 * B) return;
    int n = t < B ? users[t] : (t < 2 * B ? items[t - B] : negs[t - 2 * B]);
    int old = atomicCAS(&mapid[n], -1, -2);
    if (old == -1) mapid[n] = atomicAdd(mcnt, 1);
}

// ---------------------------------------------------------------------------
// PRE: degree counting (+ filtered deg2 count) + proj(+Wo->Vt) + cvt halves
// ---------------------------------------------------------------------------
__global__ void pre_kernel(const float* __restrict__ W_word,
                           const float* __restrict__ Wq,
                           const float* __restrict__ Wk,
                           const float* __restrict__ Wv,
                           const float* __restrict__ Wo,
                           ushort* __restrict__ Pq, ushort* __restrict__ Pk,
                           ushort* __restrict__ Vt,
                           const float* __restrict__ W_query,
                           const float* __restrict__ W_entity,
                           ushort* __restrict__ qe0b, ushort* __restrict__ e0b,
                           const int* __restrict__ p_src,
                           const int* __restrict__ p_dst,
                           const int* __restrict__ profile_dst,
                           const int* __restrict__ mapid,
                           int* __restrict__ degc, int* __restrict__ degp,
                           int* __restrict__ deg2,
                           int WORD, int Qn, int N, int E, int R,
                           int nc_blk, int npj_blk, int ncq_blk, int nce_blk) {
    int bid = blockIdx.x;
    int g = bid >> 3, j = bid & 7;
    if ((g & 3) == 3) {                       // count family
        int idx = (g >> 2) * 8 + j;
        if (idx >= nc_blk) return;
        int t = idx * 256 + threadIdx.x;
        if (t < E) {
            int s = p_src[t], d = p_dst[t];
            atomicAdd(&degc[s], 1);
            atomicAdd(&degc[d], 1);
            int md = mapid[d]; if (md >= 0) atomicAdd(&deg2[md], 1);
            int ms = mapid[s]; if (ms >= 0) atomicAdd(&deg2[ms], 1);
        }
        if (t < R) atomicAdd(&degp[profile_dst[t]], 1);
        return;
    }
    int idx = ((g >> 2) * 3 + (g & 3)) * 8 + j;
    if (idx < npj_blk) {
        int wid  = idx * 4 + (threadIdx.x >> 6);
        int lane = threadIdx.x & 63;
        if (wid >= WORD) return;
        float x = W_word[(size_t)wid * 64 + lane];
        float aq = 0.f, ak = 0.f, av = 0.f;
#pragma unroll
        for (int i = 0; i < 64; i++) {
            float xi = __shfl(x, i, 64);
            aq = fmaf(xi, Wq[i * 64 + lane], aq);
            ak = fmaf(xi, Wk[i * 64 + lane], ak);
            av = fmaf(xi, Wv[i * 64 + lane], av);
        }
        size_t o = (size_t)wid * 64 + lane;
        Pq[o] = f2bf(aq); Pk[o] = f2bf(ak);
        float vt[4] = {0.f, 0.f, 0.f, 0.f};
#pragma unroll
        for (int i = 0; i < 64; i++) {
            float vi = __shfl(av, i, 64);
            vt[i >> 4] = fmaf(vi, Wo[i * 64 + lane], vt[i >> 4]);
        }
#pragma unroll
        for (int h = 0; h < 4; h++)
            Vt[((size_t)wid * 4 + h) * 64 + lane] = f2bf(vt[h]);
    } else if (idx < npj_blk + ncq_blk) {
        int t = (idx - npj_blk) * 256 + threadIdx.x;
        if (t >= Qn * 16) return;
        int r = t >> 4, c = (t & 15) * 4;
        const float4 v = *(const float4*)(W_query + (size_t)r * 64 + c);
        ushort4 o;
        o.x = f2bf(v.x); o.y = f2bf(v.y); o.z = f2bf(v.z); o.w = f2bf(v.w);
        *(ushort4*)(qe0b + (size_t)r * 128 + c) = o;
    } else if (idx < npj_blk + ncq_blk + nce_blk) {
        int t = (idx - npj_blk - ncq_blk) * 256 + threadIdx.x;
        if (t >= N * 16) return;
        int r = t >> 4, c = (t & 15) * 4;
        const float4 v = *(const float4*)(W_entity + (size_t)r * 64 + c);
        ushort4 o;
        o.x = f2bf(v.x); o.y = f2bf(v.y); o.z = f2bf(v.z); o.w = f2bf(v.w);
        *(ushort4*)(e0b + (size_t)r * 128 + c) = o;
    }
}

// ---------------------------------------------------------------------------
// scan stage 1: per-1024-chunk sums of degp
// ---------------------------------------------------------------------------
__global__ void scan_sum(const int* __restrict__ degp, int* __restrict__ csum,
                         int N) {
    __shared__ int red[4];
    int chunk = blockIdx.x, t = threadIdx.x;
    int base = chunk * 1024;
    int v = 0;
#pragma unroll
    for (int k = 0; k < 4; k++) {
        int idx = base + t * 4 + k;
        if (idx < N) v += degp[idx];
    }
#pragma unroll
    for (int o = 32; o; o >>= 1) v += __shfl_down(v, o, 64);
    if ((t & 63) == 0) red[t >> 6] = v;
    __syncthreads();
    if (t == 0) csum[chunk] = red[0] + red[1] + red[2] + red[3];
}

// ---------------------------------------------------------------------------
// scan stage 2 (1 block): csum exclusive scan + deg2 -> offs2/cursor2
// ---------------------------------------------------------------------------
__global__ void scan_mid(int* __restrict__ csum, int nchunk,
                         const int* __restrict__ deg2,
                         int* __restrict__ offs2, int* __restrict__ cursor2,
                         int nb2) {
    __shared__ int lds[256];
    int t = threadIdx.x;
    int v = (t < nchunk) ? csum[t] : 0;
    lds[t] = v;
    __syncthreads();
    for (int o = 1; o < 256; o <<= 1) {
        int u = (t >= o) ? lds[t - o] : 0;
        __syncthreads();
        lds[t] += u;
        __syncthreads();
    }
    if (t < nchunk) csum[t] = lds[t] - v;  // exclusive
    __syncthreads();
    // deg2 scan: nb2 multiple of 256
    int k2 = nb2 >> 8;
    int s = 0;
    for (int k = 0; k < k2; k++) s += deg2[t * k2 + k];
    lds[t] = s;
    __syncthreads();
    for (int o = 1; o < 256; o <<= 1) {
        int u = (t >= o) ? lds[t - o] : 0;
        __syncthreads();
        lds[t] += u;
        __syncthreads();
    }
    int tb = lds[t] - s;
    for (int k = 0; k < k2; k++) {
        int dv = deg2[t * k2 + k];
        offs2[t * k2 + k] = tb;
        cursor2[t * k2 + k] = tb;
        tb += dv;
    }
    if (t == 255) offs2[nb2] = tb;
}

// ---------------------------------------------------------------------------
// scan stage 3: degp -> offs_r/cursor_r (reviews CSR); inv from degc
// ---------------------------------------------------------------------------
__global__ void scan_chunk(const int* __restrict__ degp,
                           const int* __restrict__ csum,
                           const int* __restrict__ degc,
                           int* __restrict__ offs_r, int* __restrict__ cursor_r,
                           float* __restrict__ inv, int N) {
    __shared__ int lds[256];
    int chunk = blockIdx.x, t = threadIdx.x;
    int base = chunk * 1024 + t * 4;
    int v0 = (base + 0 < N) ? degp[base + 0] : 0;
    int v1 = (base + 1 < N) ? degp[base + 1] : 0;
    int v2 = (base + 2 < N) ? degp[base + 2] : 0;
    int v3 = (base + 3 < N) ? degp[base + 3] : 0;
    if (base + 0 < N) inv[base + 0] = 1.0f / sqrtf((float)max(degc[base + 0], 1));
    if (base + 1 < N) inv[base + 1] = 1.0f / sqrtf((float)max(degc[base + 1], 1));
    if (base + 2 < N) inv[base + 2] = 1.0f / sqrtf((float)max(degc[base + 2], 1));
    if (base + 3 < N) inv[base + 3] = 1.0f / sqrtf((float)max(degc[base + 3], 1));
    int s = v0 + v1 + v2 + v3;
    lds[t] = s;
    __syncthreads();
    for (int o = 1; o < 256; o <<= 1) {
        int u = (t >= o) ? lds[t - o] : 0;
        __syncthreads();
        lds[t] += u;
        __syncthreads();
    }
    int tb = lds[t] - s + csum[chunk];
    int vv[4] = {v0, v1, v2, v3};
#pragma unroll
    for (int k = 0; k < 4; k++) {
        int idx = base + k;
        if (idx < N) {
            offs_r[idx] = tb; cursor_r[idx] = tb; tb += vv[k];
            if (idx == N - 1) offs_r[N] = tb;
        }
    }
}

// ---------------------------------------------------------------------------
// MFMA MHSA: one wave = TWO sequences (unchanged, verified R5/R6)
// ---------------------------------------------------------------------------
__device__ __forceinline__ void mhsa_pair(const ushort* __restrict__ Pq,
                                          const ushort* __restrict__ Pk,
                                          const ushort* __restrict__ Vt,
                                          const int* __restrict__ ids,
                                          int wid2, int lane, int mode,
                                          ushort* __restrict__ outb,
                                          float* __restrict__ outf) {
    const int l15 = lane & 15;
    const int gi  = lane >> 4;
    const int hs  = gi >> 1;
    const int dbase = (gi & 1) * 8;
    const int* idr = ids + (size_t)wid2 * 16;
    const bool valid = hs == (l15 >> 3);

    const int myid = idr[l15];
    int vid[8];
#pragma unroll
    for (int i = 0; i < 8; i++) vid[i] = idr[dbase + i];

    uint pk4[4][2];
    const f32x4 zero4 = {0.f, 0.f, 0.f, 0.f};
#pragma unroll
    for (int h = 0; h < 4; h++) {
        U8 a, b;
        if (valid) {
            a.u4 = *(const uint4*)(Pk + (size_t)myid * 64 + h * 16 + dbase);
            b.u4 = *(const uint4*)(Pq + (size_t)myid * 64 + h * 16 + dbase);
        } else {
            a.u4 = make_uint4(0, 0, 0, 0);
            b.u4 = make_uint4(0, 0, 0, 0);
        }
        f32x4 d = __builtin_amdgcn_mfma_f32_16x16x32_bf16(a.b, b.b, zero4, 0, 0, 0);
        float s0 = d[0] * 0.25f, s1 = d[1] * 0.25f;
        float s2 = d[2] * 0.25f, s3 = d[3] * 0.25f;
        if (!valid) { s0 = s1 = s2 = s3 = -1e30f; }
        float mx = fmaxf(fmaxf(s0, s1), fmaxf(s2, s3));
        mx = fmaxf(mx, __shfl_xor(mx, 16, 64));
        mx = fmaxf(mx, __shfl_xor(mx, 32, 64));
        float x0 = __expf(s0 - mx), x1 = __expf(s1 - mx);
        float x2 = __expf(s2 - mx), x3 = __expf(s3 - mx);
        float sm = x0 + x1 + x2 + x3;
        sm += __shfl_xor(sm, 16, 64);
        sm += __shfl_xor(sm, 32, 64);
        float f = 0.125f / sm;
        uint w0 = (uint)f2bf(x0 * f) | ((uint)f2bf(x1 * f) << 16);
        uint w1 = (uint)f2bf(x2 * f) | ((uint)f2bf(x3 * f) << 16);
        pk4[h][0] = valid ? w0 : 0u;
        pk4[h][1] = valid ? w1 : 0u;
    }

    const int srcA = l15 + (gi & 1) * 32;
    const int srcB = srcA + 16;
    uint aw[2][4];
#pragma unroll
    for (int P = 0; P < 2; P++) {
        uint r00 = (uint)__shfl((int)pk4[2 * P][0], srcA, 64);
        uint r01 = (uint)__shfl((int)pk4[2 * P][1], srcA, 64);
        uint r02 = (uint)__shfl((int)pk4[2 * P][0], srcB, 64);
        uint r03 = (uint)__shfl((int)pk4[2 * P][1], srcB, 64);
        uint r10 = (uint)__shfl((int)pk4[2 * P + 1][0], srcA, 64);
        uint r11 = (uint)__shfl((int)pk4[2 * P + 1][1], srcA, 64);
        uint r12 = (uint)__shfl((int)pk4[2 * P + 1][0], srcB, 64);
        uint r13 = (uint)__shfl((int)pk4[2 * P + 1][1], srcB, 64);
        aw[P][0] = hs ? r10 : r00;
        aw[P][1] = hs ? r11 : r01;
        aw[P][2] = hs ? r12 : r02;
        aw[P][3] = hs ? r13 : r03;
    }

    size_t vb[8];
#pragma unroll
    for (int i = 0; i < 8; i++) vb[i] = (size_t)vid[i] * 256;
#pragma unroll
    for (int t = 0; t < 4; t++) {
        const int col = t * 16 + l15;
        f32x4 acc = zero4;
#pragma unroll
        for (int P = 0; P < 2; P++) {
            const int h = 2 * P + hs;
            uint e[8];
#pragma unroll
            for (int i = 0; i < 8; i++) e[i] = Vt[vb[i] + h * 64 + col];
            U8 bv;
            bv.w[0] = e[0] | (e[1] << 16);
            bv.w[1] = e[2] | (e[3] << 16);
            bv.w[2] = e[4] | (e[5] << 16);
            bv.w[3] = e[6] | (e[7] << 16);
            U8 av_;
            av_.w[0] = aw[P][0]; av_.w[1] = aw[P][1];
            av_.w[2] = aw[P][2]; av_.w[3] = aw[P][3];
            acc = __builtin_amdgcn_mfma_f32_16x16x32_bf16(av_.b, bv.b, acc, 0, 0, 0);
        }
        float s = acc[0] + acc[1] + acc[2] + acc[3];
        s += __shfl_xor(s, 16, 64);
        if ((gi & 1) == 0) {
            int row = wid2 * 2 + hs;
            if (mode == 0)      outb[(size_t)row * 128 + 64 + col] = f2bf(s);
            else if (mode == 1) outb[(size_t)row * 64 + col] = f2bf(s);
            else                outf[(size_t)row * 64 + col] = s;
        }
    }
}

// ---------------------------------------------------------------------------
// MEGA: mhsa x3 (3/4 stripes) + {filtered place, scatter_rev} (1/4 stripes)
// ---------------------------------------------------------------------------
__global__ void mega_kernel(const ushort* __restrict__ Pq,
                            const ushort* __restrict__ Pk,
                            const ushort* __restrict__ Vt,
                            const int* __restrict__ query_word_ids,
                            const int* __restrict__ review_word_ids,
                            const int* __restrict__ query_words,
                            ushort* __restrict__ qe0b,
                            ushort* __restrict__ hrev,
                            float* __restrict__ qb,
                            const int* __restrict__ p_src,
                            const int* __restrict__ p_dst,
                            const int* __restrict__ p_qid,
                            const int* __restrict__ profile_dst,
                            const int* __restrict__ mapid,
                            int* __restrict__ cursor2, int2* __restrict__ list2,
                            int* __restrict__ cursor_r, int* __restrict__ rmsg,
                            int Qn, int R, int B, int E,
                            int nr_blk, int nq_blk, int nb_blk,
                            int np_blk, int nv_blk) {
    int bid = blockIdx.x;
    int g = bid >> 3, j = bid & 7;
    if ((g & 3) == 3) {                       // scatter family
        int idx = (g >> 2) * 8 + j;
        if (idx < np_blk) {
            int base = idx * 512 + threadIdx.x;
#pragma unroll
            for (int k = 0; k < 2; k++) {
                int e = base + k * 256;
                if (e < E) {
                    int s = p_src[e], d = p_dst[e];
                    int md = mapid[d], ms = mapid[s];
                    if (md >= 0)
                        list2[atomicAdd(&cursor2[md], 1)] = make_int2(s, p_qid[e]);
                    if (ms >= 0)
                        list2[atomicAdd(&cursor2[ms], 1)] = make_int2(d, -1);
                }
            }
        } else if (idx < np_blk + nv_blk) {
            int r = (idx - np_blk) * 256 + threadIdx.x;
            if (r >= R) return;
            rmsg[atomicAdd(&cursor_r[profile_dst[r]], 1)] = r;
        }
        return;
    }
    int idx = ((g >> 2) * 3 + (g & 3)) * 8 + j;
    int lane = threadIdx.x & 63;
    int w = threadIdx.x >> 6;
    if (idx < nr_blk) {
        int wid2 = idx * 4 + w;
        if (wid2 < (R >> 1))
            mhsa_pair(Pq, Pk, Vt, review_word_ids, wid2, lane, 1, hrev, nullptr);
    } else if (idx < nr_blk + nq_blk) {
        int wid2 = (idx - nr_blk) * 4 + w;
        if (wid2 < (Qn >> 1))
            mhsa_pair(Pq, Pk, Vt, query_word_ids, wid2, lane, 0, qe0b, nullptr);
    } else if (idx < nr_blk + nq_blk + nb_blk) {
        int wid2 = (idx - nr_blk - nq_blk) * 4 + w;
        if (wid2 < (B >> 1))
            mhsa_pair(Pq, Pk, Vt, query_words, wid2, lane, 2, nullptr, qb);
    }
}

// ---------------------------------------------------------------------------
// ent_h = segment_mean(hrev) -> e0b high half (bf16). 16 lanes/entity.
// ---------------------------------------------------------------------------
__global__ void entity_gather(const ushort* __restrict__ hrev,
                              const int* __restrict__ offs_r,
                              const int* __restrict__ rmsg,
                              ushort* __restrict__ e0b, int N) {
    int g = (blockIdx.x * blockDim.x + threadIdx.x) >> 4;
    int c = (threadIdx.x & 15) * 4;
    if (g >= N) return;
    int beg = offs_r[g], end = offs_r[g + 1];
    float a0 = 0.f, a1 = 0.f, a2 = 0.f, a3 = 0.f;
    for (int m = beg; m < end; m++) {
        int r = rmsg[m];
        ushort4 v = *(const ushort4*)(hrev + (size_t)r * 64 + c);
        a0 += bf2f(v.x); a1 += bf2f(v.y); a2 += bf2f(v.z); a3 += bf2f(v.w);
    }
    float s = 1.0f / (float)max(end - beg, 1);
    ushort4 o;
    o.x = f2bf(a0 * s); o.y = f2bf(a1 * s); o.z = f2bf(a2 * s); o.w = f2bf(a3 * s);
    *(ushort4*)(e0b + (size_t)g * 128 + 64 + c) = o;
}

// ---------------------------------------------------------------------------
// fused conv-gather + output: only the <=3B marked nodes. 16 lanes/slot.
// e(n,c) = 0.5*(e0b[n] + (sum msgs)*inv[n]);  slot which: 0=user,1=item,2=neg
// ---------------------------------------------------------------------------
__global__ void gather_out(const ushort* __restrict__ e0b,
                           const ushort* __restrict__ qe0b,
                           const float* __restrict__ inv,
                           const int* __restrict__ mapid,
                           const int* __restrict__ offs2,
                           const int2* __restrict__ list2,
                           const float* __restrict__ qb,
                           const int* __restrict__ users,
                           const int* __restrict__ items,
                           const int* __restrict__ negs,
                           float* __restrict__ out, int B) {
    int slot = (blockIdx.x * blockDim.x + threadIdx.x) >> 4;
    int c = (threadIdx.x & 15) * 8;
    if (slot >= 3 * B) return;
    int which = slot / B, b = slot - which * B;
    int node = which == 0 ? users[b] : (which == 1 ? items[b] : negs[b]);
    int m = mapid[node];
    int beg = offs2[m], end = offs2[m + 1];
    float a0 = 0.f, a1 = 0.f, a2 = 0.f, a3 = 0.f;
    float a4 = 0.f, a5 = 0.f, a6 = 0.f, a7 = 0.f;
    for (int i = beg; i < end; i++) {
        int2 mm = list2[i];
        float w = inv[mm.x];
        const uint4 ev = *(const uint4*)(e0b + (size_t)mm.x * 128 + c);
        if (mm.y >= 0) {
            const uint4 qv = *(const uint4*)(qe0b + (size_t)mm.y * 128 + c);
            float2 e, q;
            e = bfp2f(ev.x); q = bfp2f(qv.x); a0 += fmaf(q.x, w, e.x); a1 += fmaf(q.y, w, e.y);
            e = bfp2f(ev.y); q = bfp2f(qv.y); a2 += fmaf(q.x, w, e.x); a3 += fmaf(q.y, w, e.y);
            e = bfp2f(ev.z); q = bfp2f(qv.z); a4 += fmaf(q.x, w, e.x); a5 += fmaf(q.y, w, e.y);
            e = bfp2f(ev.w); q = bfp2f(qv.w); a6 += fmaf(q.x, w, e.x); a7 += fmaf(q.y, w, e.y);
        } else {
            float2 e;
            e = bfp2f(ev.x); a0 = fmaf(e.x, w, a0); a1 = fmaf(e.y, w, a1);
            e = bfp2f(ev.y); a2 = fmaf(e.x, w, a2); a3 = fmaf(e.y, w, a3);
            e = bfp2f(ev.z); a4 = fmaf(e.x, w, a4); a5 = fmaf(e.y, w, a5);
            e = bfp2f(ev.w); a6 = fmaf(e.x, w, a6); a7 = fmaf(e.y, w, a7);
        }
    }
    float wn = inv[node];
    const uint4 sv = *(const uint4*)(e0b + (size_t)node * 128 + c);
    float2 e0v;
    float r0, r1, r2, r3, r4, r5, r6, r7;
    e0v = bfp2f(sv.x); r0 = 0.5f * fmaf(a0, wn, e0v.x); r1 = 0.5f * fmaf(a1, wn, e0v.y);
    e0v = bfp2f(sv.y); r2 = 0.5f * fmaf(a2, wn, e0v.x); r3 = 0.5f * fmaf(a3, wn, e0v.y);
    e0v = bfp2f(sv.z); r4 = 0.5f * fmaf(a4, wn, e0v.x); r5 = 0.5f * fmaf(a5, wn, e0v.y);
    e0v = bfp2f(sv.w); r6 = 0.5f * fmaf(a6, wn, e0v.x); r7 = 0.5f * fmaf(a7, wn, e0v.y);
    if (which == 0 && c >= 64) {
        const float4 q0 = *(const float4*)(qb + (size_t)b * 64 + (c - 64));
        const float4 q1 = *(const float4*)(qb + (size_t)b * 64 + (c - 60));
        r0 += q0.x; r1 += q0.y; r2 += q0.z; r3 += q0.w;
        r4 += q1.x; r5 += q1.y; r6 += q1.z; r7 += q1.w;
    }
    float* dst = out + (size_t)which * B * 128 + (size_t)b * 128 + c;
    float4 w0; w0.x = r0; w0.y = r1; w0.z = r2; w0.w = r3;
    float4 w1; w1.x = r4; w1.y = r5; w1.z = r6; w1.w = r7;
    *(float4*)dst = w0;
    *(float4*)(dst + 4) = w1;
}

// ---------------------------------------------------------------------------
extern "C" void kernel_launch(void* const* d_in, const int* in_sizes, int n_in,
                              void* d_out, int out_size, void* d_ws, size_t ws_size,
                              hipStream_t stream) {
    const float* W_word   = (const float*)d_in[0];
    const float* W_query  = (const float*)d_in[1];
    const float* W_entity = (const float*)d_in[2];
    const float* Wq       = (const float*)d_in[3];
    const float* Wk       = (const float*)d_in[4];
    const float* Wv       = (const float*)d_in[5];
    const float* Wo       = (const float*)d_in[6];
    const int* query_word_ids  = (const int*)d_in[7];
    const int* review_word_ids = (const int*)d_in[8];
    const int* profile_dst     = (const int*)d_in[9];
    const int* p_src  = (const int*)d_in[10];
    const int* p_dst  = (const int*)d_in[11];
    const int* p_qid  = (const int*)d_in[12];
    const int* users  = (const int*)d_in[13];
    const int* items  = (const int*)d_in[14];
    const int* negs   = (const int*)d_in[15];
    const int* query_words = (const int*)d_in[16];

    const int WORD = in_sizes[0] / 64;   // 50000
    const int Qn   = in_sizes[1] / 64;   // 50000
    const int N    = in_sizes[2] / 64;   // 100000
    const int R    = in_sizes[8] / 8;    // 100000
    const int E    = in_sizes[10];       // 2000000
    const int B    = in_sizes[13];       // 1024

    const int NB2 = ((3 * B + 255) / 256) * 256;  // compact-node table size

    ushort* e0b  = (ushort*)d_ws;                       // [N,128] bf16
    ushort* qe0b = e0b + (size_t)N * 128;               // [Qn,128] bf16
    ushort* Pq   = qe0b + (size_t)Qn * 128;             // [WORD,64] bf16
    ushort* Pk   = Pq + (size_t)WORD * 64;              // [WORD,64] bf16
    ushort* Vt   = Pk + (size_t)WORD * 64;              // [WORD,4,64] bf16
    ushort* hrev = Vt + (size_t)WORD * 256;             // [R,64] bf16
    float*  qb   = (float*)(hrev + (size_t)R * 64);     // [B,64] f32
    float*  inv  = qb + (size_t)B * 64;                 // [N]
    // zero block: degc, degp, deg2, mcnt
    int* degc     = (int*)(inv + N);                    // [N]
    int* degp     = degc + N;                           // [N]
    int* deg2     = degp + N;                           // [NB2]
    int* mcnt     = deg2 + NB2;                         // [4]
    // non-zeroed:
    int* mapid    = mcnt + 4;                           // [N] memset 0xFF
    int* offs_r   = mapid + N;                          // [N+2]
    int* cursor_r = offs_r + N + 2;                     // [N]
    int* csum     = cursor_r + N;                       // [256]
    int* offs2    = csum + 256;                         // [NB2+1]
    int* cursor2  = offs2 + NB2 + 1;                    // [NB2]
    int* rmsg     = cursor2 + NB2;                      // [R]
    int2* list2   = (int2*)(rmsg + R);                  // [1M] 8 MB

    const int nchunk = (N + 1023) / 1024;               // 98

    hipMemsetAsync(degc, 0, (2 * (size_t)N + NB2 + 4) * sizeof(int), stream);
    hipMemsetAsync(mapid, 0xFF, (size_t)N * sizeof(int), stream);

    // mark output nodes (compact dedupe)
    mark_kernel<<<(3 * B + 255) / 256, 256, 0, stream>>>(users, items, negs,
                                                         mapid, mcnt, B);

    // PRE: count(+deg2 filter) + proj(+Vt) + cvt fused
    {
        int nc_blk  = (E + 255) / 256;
        int npj_blk = (WORD + 3) / 4;
        int ncq_blk = (Qn * 16 + 255) / 256;
        int nce_blk = (N * 16 + 255) / 256;
        int mh_fam  = npj_blk + ncq_blk + nce_blk;
        int T = max(4 * nc_blk, (mh_fam * 4 + 2) / 3);
        T = ((T + 31) / 32) * 32;
        pre_kernel<<<T, 256, 0, stream>>>(W_word, Wq, Wk, Wv, Wo, Pq, Pk, Vt,
                                          W_query, W_entity, qe0b, e0b,
                                          p_src, p_dst, profile_dst, mapid,
                                          degc, degp, deg2,
                                          WORD, Qn, N, E, R,
                                          nc_blk, npj_blk, ncq_blk, nce_blk);
    }

    // scans: reviews CSR + compact-node CSR + inv
    scan_sum<<<nchunk, 256, 0, stream>>>(degp, csum, N);
    scan_mid<<<1, 256, 0, stream>>>(csum, nchunk, deg2, offs2, cursor2, NB2);
    scan_chunk<<<nchunk, 256, 0, stream>>>(degp, csum, degc, offs_r, cursor_r, inv, N);

    // MEGA: MFMA-mhsa x3 + {filtered message place, scatter_rev}
    {
        int nr_blk = (R / 2 + 3) / 4;
        int nq_blk = (Qn / 2 + 3) / 4;
        int nb_blk = (B / 2 + 3) / 4;
        int np_blk = (E + 511) / 512;
        int nv_blk = (R + 255) / 256;
        int sc = np_blk + nv_blk;
        int mh = nr_blk + nq_blk + nb_blk;
        int T = max(4 * sc, (mh * 4 + 2) / 3);
        T = ((T + 31) / 32) * 32;
        mega_kernel<<<T, 256, 0, stream>>>(Pq, Pk, Vt,
                                           query_word_ids, review_word_ids, query_words,
                                           qe0b, hrev, qb,
                                           p_src, p_dst, p_qid, profile_dst, mapid,
                                           cursor2, list2, cursor_r, rmsg,
                                           Qn, R, B, E,
                                           nr_blk, nq_blk, nb_blk, np_blk, nv_blk);
    }

    // ent_h -> e0b high half
    entity_gather<<<(N * 16 + 255) / 256, 256, 0, stream>>>(hrev, offs_r, rmsg, e0b, N);

    // fused conv-gather + output (only marked nodes)
    gather_out<<<(3 * B * 16 + 255) / 256, 256, 0, stream>>>(e0b, qe0b, inv,
                                                             mapid, offs2, list2,
                                                             qb, users, items, negs,
                                                             (float*)d_out, B);
}

// Round 8
// 440.184 us; speedup vs baseline: 1.9244x; 1.1583x over previous
//
#include <hip/hip_runtime.h>

typedef unsigned int uint;
typedef unsigned short ushort;

typedef __bf16 bf16x8 __attribute__((ext_vector_type(8)));
typedef float f32x4 __attribute__((ext_vector_type(4)));
union U8 { uint4 u4; uint w[4]; bf16x8 b; };

__device__ __forceinline__ float bf2f(ushort u) {
    return __uint_as_float(((uint)u) << 16);
}
__device__ __forceinline__ float2 bfp2f(uint u) {
    float2 r;
    r.x = __uint_as_float(u << 16);
    r.y = __uint_as_float(u & 0xffff0000u);
    return r;
}
__device__ __forceinline__ ushort f2bf(float f) {
    uint u = __float_as_uint(f);
    return (ushort)((u + 0x7fffu + ((u >> 16) & 1u)) >> 16);  // RNE
}
__device__ __forceinline__ uint4 pack8(float4 a, float4 b) {
    uint4 u;
    u.x = (uint)f2bf(a.x) | ((uint)f2bf(a.y) << 16);
    u.y = (uint)f2bf(a.z) | ((uint)f2bf(a.w) << 16);
    u.z = (uint)f2bf(b.x) | ((uint)f2bf(b.y) << 16);
    u.w = (uint)f2bf(b.z) | ((uint)f2bf(b.w) << 16);
    return u;
}

// ---------------------------------------------------------------------------
// mark output nodes: dedupe via CAS, assign compact ids
// ---------------------------------------------------------------------------
__global__ void mark_kernel(const int* __restrict__ users,
                            const int* __restrict__ items,
                            const int* __restrict__ negs,
                            int* __restrict__ mapid, int* __restrict__ mcnt,
                            int B) {
    int t = blockIdx.x * blockDim.x + threadIdx.x;
    if (t >= 3 * B) return;
    int n = t < B ? users[t] : (t < 2 * B ? items[t - B] : negs[t - 2 * B]);
    int old = atomicCAS(&mapid[n], -1, -2);
    if (old == -1) mapid[n] = atomicAdd(mcnt, 1);
}

// ---------------------------------------------------------------------------
// weight swizzle: B-fragment layout for MFMA.
// wsw  : [Wq|Wk|Wv] 12 col-tiles x 2 k-halves; frag elem (lane,i) =
//        W[kh*32+(lane>>4)*8+i][(ct&3)*16+(lane&15)]
// wswo : Wo 4 col-tiles x 2 k-halves, same layout
// ---------------------------------------------------------------------------
__global__ void wswz_kernel(const float* __restrict__ Wq,
                            const float* __restrict__ Wk,
                            const float* __restrict__ Wv,
                            const float* __restrict__ Wo,
                            ushort* __restrict__ wsw, ushort* __restrict__ wswo) {
    int e = blockIdx.x * 256 + threadIdx.x;   // 12288 + 4096 = 16384
    if (e < 12288) {
        int f = e >> 9, r = e & 511;
        int lane = r >> 3, i = r & 7;
        int ct = f >> 1, kh = f & 1;
        int k = kh * 32 + (lane >> 4) * 8 + i;
        int col = (ct & 3) * 16 + (lane & 15);
        const float* W = ct < 4 ? Wq : (ct < 8 ? Wk : Wv);
        wsw[f * 512 + lane * 8 + i] = f2bf(W[k * 64 + col]);
    } else if (e < 16384) {
        int e2 = e - 12288;
        int f = e2 >> 9, r = e2 & 511;
        int lane = r >> 3, i = r & 7;
        int ct = f >> 1, kh = f & 1;
        int k = kh * 32 + (lane >> 4) * 8 + i;
        int col = ct * 16 + (lane & 15);
        wswo[f * 512 + lane * 8 + i] = f2bf(Wo[k * 64 + col]);
    }
}

// ---------------------------------------------------------------------------
// PRE: {degree counts (+deg2 filter)} | {MFMA proj -> Pq/Pk/Pv, cvt halves}
// stripe (g&3)==3 -> count family (2 edges/thread), else mh family.
// ---------------------------------------------------------------------------
__global__ void pre_kernel(const float* __restrict__ W_word,
                           const ushort* __restrict__ wsw,
                           ushort* __restrict__ Pq, ushort* __restrict__ Pk,
                           ushort* __restrict__ Pv,
                           const float* __restrict__ W_query,
                           const float* __restrict__ W_entity,
                           ushort* __restrict__ qe0b, ushort* __restrict__ e0b,
                           const int* __restrict__ p_src,
                           const int* __restrict__ p_dst,
                           const int* __restrict__ profile_dst,
                           const int* __restrict__ mapid,
                           int* __restrict__ degc, int* __restrict__ degp,
                           int* __restrict__ deg2,
                           int WORD, int Qn, int N, int E, int R,
                           int nc_blk, int npj_blk, int ncq_blk, int nce_blk) {
    int bid = blockIdx.x;
    int g = bid >> 3, j = bid & 7;
    if ((g & 3) == 3) {                       // count family
        int idx = (g >> 2) * 8 + j;
        if (idx >= nc_blk) return;
        int base = idx * 512 + threadIdx.x;
#pragma unroll
        for (int k = 0; k < 2; k++) {
            int t = base + k * 256;
            if (t < E) {
                int s = p_src[t], d = p_dst[t];
                atomicAdd(&degc[s], 1);
                atomicAdd(&degc[d], 1);
                int md = mapid[d]; if (md >= 0) atomicAdd(&deg2[md], 1);
                int ms = mapid[s]; if (ms >= 0) atomicAdd(&deg2[ms], 1);
            }
            if (t < R) atomicAdd(&degp[profile_dst[t]], 1);
        }
        return;
    }
    int idx = ((g >> 2) * 3 + (g & 3)) * 8 + j;
    if (idx < npj_blk) {
        // MFMA proj: 16-row tile per wave, [16x64]@[64x192]
        int tile = idx * 4 + (threadIdx.x >> 6);
        if (tile * 16 >= WORD) return;
        int lane = threadIdx.x & 63, l15 = lane & 15, gi = lane >> 4;
        const float* xr = W_word + ((size_t)tile * 16 + l15) * 64 + gi * 8;
        U8 a0, a1;
        a0.u4 = pack8(*(const float4*)(xr), *(const float4*)(xr + 4));
        a1.u4 = pack8(*(const float4*)(xr + 32), *(const float4*)(xr + 36));
        const f32x4 zero4 = {0.f, 0.f, 0.f, 0.f};
#pragma unroll
        for (int ct = 0; ct < 12; ct++) {
            U8 b0, b1;
            b0.u4 = *(const uint4*)(wsw + (ct * 2 + 0) * 512 + lane * 8);
            b1.u4 = *(const uint4*)(wsw + (ct * 2 + 1) * 512 + lane * 8);
            f32x4 acc = __builtin_amdgcn_mfma_f32_16x16x32_bf16(a0.b, b0.b, zero4, 0, 0, 0);
            acc = __builtin_amdgcn_mfma_f32_16x16x32_bf16(a1.b, b1.b, acc, 0, 0, 0);
            ushort* dst = ct < 4 ? Pq : (ct < 8 ? Pk : Pv);
            int col = (ct & 3) * 16 + l15;
#pragma unroll
            for (int r = 0; r < 4; r++)
                dst[((size_t)tile * 16 + gi * 4 + r) * 64 + col] = f2bf(acc[r]);
        }
    } else if (idx < npj_blk + ncq_blk) {
        int t = (idx - npj_blk) * 256 + threadIdx.x;
        if (t >= Qn * 16) return;
        int r = t >> 4, c = (t & 15) * 4;
        const float4 v = *(const float4*)(W_query + (size_t)r * 64 + c);
        ushort4 o;
        o.x = f2bf(v.x); o.y = f2bf(v.y); o.z = f2bf(v.z); o.w = f2bf(v.w);
        *(ushort4*)(qe0b + (size_t)r * 128 + c) = o;
    } else if (idx < npj_blk + ncq_blk + nce_blk) {
        int t = (idx - npj_blk - ncq_blk) * 256 + threadIdx.x;
        if (t >= N * 16) return;
        int r = t >> 4, c = (t & 15) * 4;
        const float4 v = *(const float4*)(W_entity + (size_t)r * 64 + c);
        ushort4 o;
        o.x = f2bf(v.x); o.y = f2bf(v.y); o.z = f2bf(v.z); o.w = f2bf(v.w);
        *(ushort4*)(e0b + (size_t)r * 128 + c) = o;
    }
}

// ---------------------------------------------------------------------------
// scan stage 1: per-1024-chunk sums of degp
// ---------------------------------------------------------------------------
__global__ void scan_sum(const int* __restrict__ degp, int* __restrict__ csum,
                         int N) {
    __shared__ int red[4];
    int chunk = blockIdx.x, t = threadIdx.x;
    int base = chunk * 1024;
    int v = 0;
#pragma unroll
    for (int k = 0; k < 4; k++) {
        int idx = base + t * 4 + k;
        if (idx < N) v += degp[idx];
    }
#pragma unroll
    for (int o = 32; o; o >>= 1) v += __shfl_down(v, o, 64);
    if ((t & 63) == 0) red[t >> 6] = v;
    __syncthreads();
    if (t == 0) csum[chunk] = red[0] + red[1] + red[2] + red[3];
}

// ---------------------------------------------------------------------------
// scan stage 2 (1 block): csum exclusive + deg2 -> offs2/cursor2
// ---------------------------------------------------------------------------
__global__ void scan_mid(int* __restrict__ csum, int nchunk,
                         const int* __restrict__ deg2,
                         int* __restrict__ offs2, int* __restrict__ cursor2,
                         int nb2) {
    __shared__ int lds[256];
    int t = threadIdx.x;
    int v = (t < nchunk) ? csum[t] : 0;
    lds[t] = v;
    __syncthreads();
    for (int o = 1; o < 256; o <<= 1) {
        int u = (t >= o) ? lds[t - o] : 0;
        __syncthreads();
        lds[t] += u;
        __syncthreads();
    }
    if (t < nchunk) csum[t] = lds[t] - v;  // exclusive
    __syncthreads();
    int k2 = nb2 >> 8;
    int s = 0;
    for (int k = 0; k < k2; k++) s += deg2[t * k2 + k];
    lds[t] = s;
    __syncthreads();
    for (int o = 1; o < 256; o <<= 1) {
        int u = (t >= o) ? lds[t - o] : 0;
        __syncthreads();
        lds[t] += u;
        __syncthreads();
    }
    int tb = lds[t] - s;
    for (int k = 0; k < k2; k++) {
        int dv = deg2[t * k2 + k];
        offs2[t * k2 + k] = tb;
        cursor2[t * k2 + k] = tb;
        tb += dv;
    }
    if (t == 255) offs2[nb2] = tb;
}

// ---------------------------------------------------------------------------
// scan stage 3: degp -> offs_r/cursor_r; inv from degc
// ---------------------------------------------------------------------------
__global__ void scan_chunk(const int* __restrict__ degp,
                           const int* __restrict__ csum,
                           const int* __restrict__ degc,
                           int* __restrict__ offs_r, int* __restrict__ cursor_r,
                           float* __restrict__ inv, int N) {
    __shared__ int lds[256];
    int chunk = blockIdx.x, t = threadIdx.x;
    int base = chunk * 1024 + t * 4;
    int v0 = (base + 0 < N) ? degp[base + 0] : 0;
    int v1 = (base + 1 < N) ? degp[base + 1] : 0;
    int v2 = (base + 2 < N) ? degp[base + 2] : 0;
    int v3 = (base + 3 < N) ? degp[base + 3] : 0;
    if (base + 0 < N) inv[base + 0] = 1.0f / sqrtf((float)max(degc[base + 0], 1));
    if (base + 1 < N) inv[base + 1] = 1.0f / sqrtf((float)max(degc[base + 1], 1));
    if (base + 2 < N) inv[base + 2] = 1.0f / sqrtf((float)max(degc[base + 2], 1));
    if (base + 3 < N) inv[base + 3] = 1.0f / sqrtf((float)max(degc[base + 3], 1));
    int s = v0 + v1 + v2 + v3;
    lds[t] = s;
    __syncthreads();
    for (int o = 1; o < 256; o <<= 1) {
        int u = (t >= o) ? lds[t - o] : 0;
        __syncthreads();
        lds[t] += u;
        __syncthreads();
    }
    int tb = lds[t] - s + csum[chunk];
    int vv[4] = {v0, v1, v2, v3};
#pragma unroll
    for (int k = 0; k < 4; k++) {
        int idx = base + k;
        if (idx < N) {
            offs_r[idx] = tb; cursor_r[idx] = tb; tb += vv[k];
            if (idx == N - 1) offs_r[N] = tb;
        }
    }
}

// ---------------------------------------------------------------------------
// MFMA MHSA (pre-Wo): wave = 2 sequences; outputs om rows [seq][64] bf16.
// scores identical to R5/R6 (verified); PV uses Pv with k=(seq,word) packing
// (half-k zeroed), one MFMA per head.
// ---------------------------------------------------------------------------
__device__ __forceinline__ void mhsa_pair(const ushort* __restrict__ Pq,
                                          const ushort* __restrict__ Pk,
                                          const ushort* __restrict__ Pv,
                                          const int* __restrict__ ids,
                                          int wid2, int lane,
                                          ushort* __restrict__ outb) {
    const int l15 = lane & 15;
    const int gi  = lane >> 4;
    const int hs  = gi >> 1;
    const int dbase = (gi & 1) * 8;
    const int* idr = ids + (size_t)wid2 * 16;
    const bool valid = hs == (l15 >> 3);

    const int myid = idr[l15];
    int vid[8];
#pragma unroll
    for (int i = 0; i < 8; i++) vid[i] = idr[dbase + i];

    uint pk4[4][2];
    const f32x4 zero4 = {0.f, 0.f, 0.f, 0.f};
#pragma unroll
    for (int h = 0; h < 4; h++) {
        U8 a, b;
        if (valid) {
            a.u4 = *(const uint4*)(Pk + (size_t)myid * 64 + h * 16 + dbase);
            b.u4 = *(const uint4*)(Pq + (size_t)myid * 64 + h * 16 + dbase);
        } else {
            a.u4 = make_uint4(0, 0, 0, 0);
            b.u4 = make_uint4(0, 0, 0, 0);
        }
        f32x4 d = __builtin_amdgcn_mfma_f32_16x16x32_bf16(a.b, b.b, zero4, 0, 0, 0);
        float s0 = d[0] * 0.25f, s1 = d[1] * 0.25f;
        float s2 = d[2] * 0.25f, s3 = d[3] * 0.25f;
        if (!valid) { s0 = s1 = s2 = s3 = -1e30f; }
        float mx = fmaxf(fmaxf(s0, s1), fmaxf(s2, s3));
        mx = fmaxf(mx, __shfl_xor(mx, 16, 64));
        mx = fmaxf(mx, __shfl_xor(mx, 32, 64));
        float x0 = __expf(s0 - mx), x1 = __expf(s1 - mx);
        float x2 = __expf(s2 - mx), x3 = __expf(s3 - mx);
        float sm = x0 + x1 + x2 + x3;
        sm += __shfl_xor(sm, 16, 64);
        sm += __shfl_xor(sm, 32, 64);
        float f = 0.125f / sm;
        uint w0 = (uint)f2bf(x0 * f) | ((uint)f2bf(x1 * f) << 16);
        uint w1 = (uint)f2bf(x2 * f) | ((uint)f2bf(x3 * f) << 16);
        pk4[h][0] = valid ? w0 : 0u;
        pk4[h][1] = valid ? w1 : 0u;
    }

    // PV per head t: A'' k=(s,m) 16 real + 16 zero; B'' = Pv rows
    const int srcA = l15 + (gi & 1) * 32;
    const int srcB = srcA + 16;
    const bool hi = gi >= 2;
    size_t vb[8];
#pragma unroll
    for (int i = 0; i < 8; i++) vb[i] = (size_t)vid[i] * 64;
#pragma unroll
    for (int t = 0; t < 4; t++) {
        uint aw0 = (uint)__shfl((int)pk4[t][0], srcA, 64);
        uint aw1 = (uint)__shfl((int)pk4[t][1], srcA, 64);
        uint aw2 = (uint)__shfl((int)pk4[t][0], srcB, 64);
        uint aw3 = (uint)__shfl((int)pk4[t][1], srcB, 64);
        U8 av_;
        av_.w[0] = hi ? 0u : aw0; av_.w[1] = hi ? 0u : aw1;
        av_.w[2] = hi ? 0u : aw2; av_.w[3] = hi ? 0u : aw3;
        uint e[8];
#pragma unroll
        for (int i = 0; i < 8; i++)
            e[i] = hi ? 0u : (uint)Pv[vb[i] + t * 16 + l15];
        U8 bv;
        bv.w[0] = e[0] | (e[1] << 16);
        bv.w[1] = e[2] | (e[3] << 16);
        bv.w[2] = e[4] | (e[5] << 16);
        bv.w[3] = e[6] | (e[7] << 16);
        f32x4 acc = __builtin_amdgcn_mfma_f32_16x16x32_bf16(av_.b, bv.b, zero4, 0, 0, 0);
        float s = acc[0] + acc[1] + acc[2] + acc[3];
        s += __shfl_xor(s, 16, 64);
        if ((gi & 1) == 0) {
            int row = wid2 * 2 + hs;
            outb[(size_t)row * 64 + t * 16 + l15] = f2bf(s);
        }
    }
}

// ---------------------------------------------------------------------------
// MEGA: mhsa x3 (3/4 stripes) + {filtered place, scatter_rev} (1/4)
// ---------------------------------------------------------------------------
__global__ void mega_kernel(const ushort* __restrict__ Pq,
                            const ushort* __restrict__ Pk,
                            const ushort* __restrict__ Pv,
                            const int* __restrict__ query_word_ids,
                            const int* __restrict__ review_word_ids,
                            const int* __restrict__ query_words,
                            ushort* __restrict__ hqom,
                            ushort* __restrict__ hrev,
                            ushort* __restrict__ omb,
                            const int* __restrict__ p_src,
                            const int* __restrict__ p_dst,
                            const int* __restrict__ p_qid,
                            const int* __restrict__ profile_dst,
                            const int* __restrict__ mapid,
                            int* __restrict__ cursor2, int2* __restrict__ list2,
                            int* __restrict__ cursor_r, int* __restrict__ rmsg,
                            int Qn, int R, int B, int E,
                            int nr_blk, int nq_blk, int nb_blk,
                            int np_blk, int nv_blk) {
    int bid = blockIdx.x;
    int g = bid >> 3, j = bid & 7;
    if ((g & 3) == 3) {                       // scatter family
        int idx = (g >> 2) * 8 + j;
        if (idx < np_blk) {
            int base = idx * 512 + threadIdx.x;
#pragma unroll
            for (int k = 0; k < 2; k++) {
                int e = base + k * 256;
                if (e < E) {
                    int s = p_src[e], d = p_dst[e];
                    int md = mapid[d], ms = mapid[s];
                    if (md >= 0)
                        list2[atomicAdd(&cursor2[md], 1)] = make_int2(s, p_qid[e]);
                    if (ms >= 0)
                        list2[atomicAdd(&cursor2[ms], 1)] = make_int2(d, -1);
                }
            }
        } else if (idx < np_blk + nv_blk) {
            int r = (idx - np_blk) * 256 + threadIdx.x;
            if (r >= R) return;
            rmsg[atomicAdd(&cursor_r[profile_dst[r]], 1)] = r;
        }
        return;
    }
    int idx = ((g >> 2) * 3 + (g & 3)) * 8 + j;
    int lane = threadIdx.x & 63;
    int w = threadIdx.x >> 6;
    if (idx < nr_blk) {
        int wid2 = idx * 4 + w;
        if (wid2 < (R >> 1))
            mhsa_pair(Pq, Pk, Pv, review_word_ids, wid2, lane, hrev);
    } else if (idx < nr_blk + nq_blk) {
        int wid2 = (idx - nr_blk) * 4 + w;
        if (wid2 < (Qn >> 1))
            mhsa_pair(Pq, Pk, Pv, query_word_ids, wid2, lane, hqom);
    } else if (idx < nr_blk + nq_blk + nb_blk) {
        int wid2 = (idx - nr_blk - nq_blk) * 4 + w;
        if (wid2 < (B >> 1))
            mhsa_pair(Pq, Pk, Pv, query_words, wid2, lane, omb);
    }
}

// ---------------------------------------------------------------------------
// entity mean of hrev(om) -> eom [N][64] bf16. 16 lanes/entity.
// ---------------------------------------------------------------------------
__global__ void entity_gather(const ushort* __restrict__ hrev,
                              const int* __restrict__ offs_r,
                              const int* __restrict__ rmsg,
                              ushort* __restrict__ eom, int N) {
    int g = (blockIdx.x * blockDim.x + threadIdx.x) >> 4;
    int c = (threadIdx.x & 15) * 4;
    if (g >= N) return;
    int beg = offs_r[g], end = offs_r[g + 1];
    float a0 = 0.f, a1 = 0.f, a2 = 0.f, a3 = 0.f;
    for (int m = beg; m < end; m++) {
        int r = rmsg[m];
        ushort4 v = *(const ushort4*)(hrev + (size_t)r * 64 + c);
        a0 += bf2f(v.x); a1 += bf2f(v.y); a2 += bf2f(v.z); a3 += bf2f(v.w);
    }
    float s = 1.0f / (float)max(end - beg, 1);
    ushort4 o;
    o.x = f2bf(a0 * s); o.y = f2bf(a1 * s); o.z = f2bf(a2 * s); o.w = f2bf(a3 * s);
    *(ushort4*)(eom + (size_t)g * 64 + c) = o;
}

// ---------------------------------------------------------------------------
// apply Wo via MFMA to all om rows: eom->e0b high, hqom->qe0b high, omb->qb
// regions are 16-row aligned (N, Qn, B all divisible by 16).
// ---------------------------------------------------------------------------
__global__ void wo_kernel(const ushort* __restrict__ eom,
                          const ushort* __restrict__ hqom,
                          const ushort* __restrict__ omb,
                          const ushort* __restrict__ wswo,
                          ushort* __restrict__ e0b, ushort* __restrict__ qe0b,
                          float* __restrict__ qb, int N, int Qn, int B) {
    int tile = blockIdx.x * 4 + (threadIdx.x >> 6);
    int ntile = (N + Qn + B) >> 4;
    if (tile >= ntile) return;
    int lane = threadIdx.x & 63, l15 = lane & 15, gi = lane >> 4;
    int row0 = tile << 4;
    int region; int rb;
    const ushort* src;
    if (row0 < N)            { region = 0; rb = row0;            src = eom; }
    else if (row0 < N + Qn)  { region = 1; rb = row0 - N;        src = hqom; }
    else                     { region = 2; rb = row0 - N - Qn;   src = omb; }
    const ushort* sr = src + ((size_t)rb + l15) * 64;
    U8 a0, a1;
    a0.u4 = *(const uint4*)(sr + gi * 8);
    a1.u4 = *(const uint4*)(sr + 32 + gi * 8);
    const f32x4 zero4 = {0.f, 0.f, 0.f, 0.f};
#pragma unroll
    for (int ct = 0; ct < 4; ct++) {
        U8 b0, b1;
        b0.u4 = *(const uint4*)(wswo + (ct * 2 + 0) * 512 + lane * 8);
        b1.u4 = *(const uint4*)(wswo + (ct * 2 + 1) * 512 + lane * 8);
        f32x4 acc = __builtin_amdgcn_mfma_f32_16x16x32_bf16(a0.b, b0.b, zero4, 0, 0, 0);
        acc = __builtin_amdgcn_mfma_f32_16x16x32_bf16(a1.b, b1.b, acc, 0, 0, 0);
        int col = ct * 16 + l15;
#pragma unroll
        for (int r = 0; r < 4; r++) {
            int row = rb + gi * 4 + r;
            if (region == 0)      e0b[(size_t)row * 128 + 64 + col] = f2bf(acc[r]);
            else if (region == 1) qe0b[(size_t)row * 128 + 64 + col] = f2bf(acc[r]);
            else                  qb[(size_t)row * 64 + col] = acc[r];
        }
    }
}

// ---------------------------------------------------------------------------
// fused conv-gather + output for the <=3B marked nodes. 16 lanes/slot.
// ---------------------------------------------------------------------------
__global__ void gather_out(const ushort* __restrict__ e0b,
                           const ushort* __restrict__ qe0b,
                           const float* __restrict__ inv,
                           const int* __restrict__ mapid,
                           const int* __restrict__ offs2,
                           const int2* __restrict__ list2,
                           const float* __restrict__ qb,
                           const int* __restrict__ users,
                           const int* __restrict__ items,
                           const int* __restrict__ negs,
                           float* __restrict__ out, int B) {
    int slot = (blockIdx.x * blockDim.x + threadIdx.x) >> 4;
    int c = (threadIdx.x & 15) * 8;
    if (slot >= 3 * B) return;
    int which = slot / B, b = slot - which * B;
    int node = which == 0 ? users[b] : (which == 1 ? items[b] : negs[b]);
    int m = mapid[node];
    int beg = offs2[m], end = offs2[m + 1];
    float a0 = 0.f, a1 = 0.f, a2 = 0.f, a3 = 0.f;
    float a4 = 0.f, a5 = 0.f, a6 = 0.f, a7 = 0.f;
    for (int i = beg; i < end; i++) {
        int2 mm = list2[i];
        float w = inv[mm.x];
        const uint4 ev = *(const uint4*)(e0b + (size_t)mm.x * 128 + c);
        if (mm.y >= 0) {
            const uint4 qv = *(const uint4*)(qe0b + (size_t)mm.y * 128 + c);
            float2 e, q;
            e = bfp2f(ev.x); q = bfp2f(qv.x); a0 += fmaf(q.x, w, e.x); a1 += fmaf(q.y, w, e.y);
            e = bfp2f(ev.y); q = bfp2f(qv.y); a2 += fmaf(q.x, w, e.x); a3 += fmaf(q.y, w, e.y);
            e = bfp2f(ev.z); q = bfp2f(qv.z); a4 += fmaf(q.x, w, e.x); a5 += fmaf(q.y, w, e.y);
            e = bfp2f(ev.w); q = bfp2f(qv.w); a6 += fmaf(q.x, w, e.x); a7 += fmaf(q.y, w, e.y);
        } else {
            float2 e;
            e = bfp2f(ev.x); a0 = fmaf(e.x, w, a0); a1 = fmaf(e.y, w, a1);
            e = bfp2f(ev.y); a2 = fmaf(e.x, w, a2); a3 = fmaf(e.y, w, a3);
            e = bfp2f(ev.z); a4 = fmaf(e.x, w, a4); a5 = fmaf(e.y, w, a5);
            e = bfp2f(ev.w); a6 = fmaf(e.x, w, a6); a7 = fmaf(e.y, w, a7);
        }
    }
    float wn = inv[node];
    const uint4 sv = *(const uint4*)(e0b + (size_t)node * 128 + c);
    float2 e0v;
    float r0, r1, r2, r3, r4, r5, r6, r7;
    e0v = bfp2f(sv.x); r0 = 0.5f * fmaf(a0, wn, e0v.x); r1 = 0.5f * fmaf(a1, wn, e0v.y);
    e0v = bfp2f(sv.y); r2 = 0.5f * fmaf(a2, wn, e0v.x); r3 = 0.5f * fmaf(a3, wn, e0v.y);
    e0v = bfp2f(sv.z); r4 = 0.5f * fmaf(a4, wn, e0v.x); r5 = 0.5f * fmaf(a5, wn, e0v.y);
    e0v = bfp2f(sv.w); r6 = 0.5f * fmaf(a6, wn, e0v.x); r7 = 0.5f * fmaf(a7, wn, e0v.y);
    if (which == 0 && c >= 64) {
        const float4 q0 = *(const float4*)(qb + (size_t)b * 64 + (c - 64));
        const float4 q1 = *(const float4*)(qb + (size_t)b * 64 + (c - 60));
        r0 += q0.x; r1 += q0.y; r2 += q0.z; r3 += q0.w;
        r4 += q1.x; r5 += q1.y; r6 += q1.z; r7 += q1.w;
    }
    float* dst = out + (size_t)which * B * 128 + (size_t)b * 128 + c;
    float4 w0; w0.x = r0; w0.y = r1; w0.z = r2; w0.w = r3;
    float4 w1; w1.x = r4; w1.y = r5; w1.z = r6; w1.w = r7;
    *(float4*)dst = w0;
    *(float4*)(dst + 4) = w1;
}

// ---------------------------------------------------------------------------
extern "C" void kernel_launch(void* const* d_in, const int* in_sizes, int n_in,
                              void* d_out, int out_size, void* d_ws, size_t ws_size,
                              hipStream_t stream) {
    const float* W_word   = (const float*)d_in[0];
    const float* W_query  = (const float*)d_in[1];
    const float* W_entity = (const float*)d_in[2];
    const float* Wq       = (const float*)d_in[3];
    const float* Wk       = (const float*)d_in[4];
    const float* Wv       = (const float*)d_in[5];
    const float* Wo       = (const float*)d_in[6];
    const int* query_word_ids  = (const int*)d_in[7];
    const int* review_word_ids = (const int*)d_in[8];
    const int* profile_dst     = (const int*)d_in[9];
    const int* p_src  = (const int*)d_in[10];
    const int* p_dst  = (const int*)d_in[11];
    const int* p_qid  = (const int*)d_in[12];
    const int* users  = (const int*)d_in[13];
    const int* items  = (const int*)d_in[14];
    const int* negs   = (const int*)d_in[15];
    const int* query_words = (const int*)d_in[16];

    const int WORD = in_sizes[0] / 64;   // 50000
    const int Qn   = in_sizes[1] / 64;   // 50000
    const int N    = in_sizes[2] / 64;   // 100000
    const int R    = in_sizes[8] / 8;    // 100000
    const int E    = in_sizes[10];       // 2000000
    const int B    = in_sizes[13];       // 1024

    const int NB2 = ((3 * B + 255) / 256) * 256;

    ushort* e0b  = (ushort*)d_ws;                       // [N,128]
    ushort* qe0b = e0b + (size_t)N * 128;               // [Qn,128]
    ushort* Pq   = qe0b + (size_t)Qn * 128;             // [WORD,64]
    ushort* Pk   = Pq + (size_t)WORD * 64;              // [WORD,64]
    ushort* Pv   = Pk + (size_t)WORD * 64;              // [WORD,64]
    ushort* hrev = Pv + (size_t)WORD * 64;              // [R,64]   om
    ushort* hqom = hrev + (size_t)R * 64;               // [Qn,64]  om
    ushort* omb  = hqom + (size_t)Qn * 64;              // [B,64]   om
    ushort* eom  = omb + (size_t)B * 64;                // [N,64]   om mean
    ushort* wsw  = eom + (size_t)N * 64;                // [12288]
    ushort* wswo = wsw + 12288;                         // [4096]
    float*  qb   = (float*)(wswo + 4096);               // [B,64] f32
    float*  inv  = qb + (size_t)B * 64;                 // [N]
    int* degc     = (int*)(inv + N);                    // [N]   (zero block)
    int* degp     = degc + N;                           // [N]
    int* deg2     = degp + N;                           // [NB2]
    int* mcnt     = deg2 + NB2;                         // [4]
    int* mapid    = mcnt + 4;                           // [N] memset 0xFF
    int* offs_r   = mapid + N;                          // [N+2]
    int* cursor_r = offs_r + N + 2;                     // [N]
    int* csum     = cursor_r + N;                       // [256]
    int* offs2    = csum + 256;                         // [NB2+2]
    int* cursor2  = offs2 + NB2 + 2;                    // [NB2]
    int* rmsg     = cursor2 + NB2;                      // [R]
    int2* list2   = (int2*)(rmsg + R);                  // filtered msgs

    const int nchunk = (N + 1023) / 1024;               // 98

    hipMemsetAsync(degc, 0, (2 * (size_t)N + NB2 + 4) * sizeof(int), stream);
    hipMemsetAsync(mapid, 0xFF, (size_t)N * sizeof(int), stream);

    mark_kernel<<<(3 * B + 255) / 256, 256, 0, stream>>>(users, items, negs,
                                                         mapid, mcnt, B);
    wswz_kernel<<<64, 256, 0, stream>>>(Wq, Wk, Wv, Wo, wsw, wswo);

    // PRE: count(+deg2) | MFMA proj + cvt
    {
        int nc_blk  = (E + 511) / 512;                  // 3907
        int npj_blk = (WORD / 16 + 3) / 4;              // 782
        int ncq_blk = (Qn * 16 + 255) / 256;            // 3125
        int nce_blk = (N * 16 + 255) / 256;             // 6250
        int mh_fam  = npj_blk + ncq_blk + nce_blk;      // 10157
        int T = max(4 * nc_blk, (mh_fam * 4 + 2) / 3);
        T = ((T + 31) / 32) * 32;
        pre_kernel<<<T, 256, 0, stream>>>(W_word, wsw, Pq, Pk, Pv,
                                          W_query, W_entity, qe0b, e0b,
                                          p_src, p_dst, profile_dst, mapid,
                                          degc, degp, deg2,
                                          WORD, Qn, N, E, R,
                                          nc_blk, npj_blk, ncq_blk, nce_blk);
    }

    scan_sum<<<nchunk, 256, 0, stream>>>(degp, csum, N);
    scan_mid<<<1, 256, 0, stream>>>(csum, nchunk, deg2, offs2, cursor2, NB2);
    scan_chunk<<<nchunk, 256, 0, stream>>>(degp, csum, degc, offs_r, cursor_r, inv, N);

    // MEGA: mhsa x3 + {filtered place, scatter_rev}
    {
        int nr_blk = (R / 2 + 3) / 4;
        int nq_blk = (Qn / 2 + 3) / 4;
        int nb_blk = (B / 2 + 3) / 4;
        int np_blk = (E + 511) / 512;
        int nv_blk = (R + 255) / 256;
        int sc = np_blk + nv_blk;
        int mh = nr_blk + nq_blk + nb_blk;
        int T = max(4 * sc, (mh * 4 + 2) / 3);
        T = ((T + 31) / 32) * 32;
        mega_kernel<<<T, 256, 0, stream>>>(Pq, Pk, Pv,
                                           query_word_ids, review_word_ids, query_words,
                                           hqom, hrev, omb,
                                           p_src, p_dst, p_qid, profile_dst, mapid,
                                           cursor2, list2, cursor_r, rmsg,
                                           Qn, R, B, E,
                                           nr_blk, nq_blk, nb_blk, np_blk, nv_blk);
    }

    // entity mean (om) -> eom
    entity_gather<<<(N * 16 + 255) / 256, 256, 0, stream>>>(hrev, offs_r, rmsg, eom, N);

    // apply Wo: eom/hqom/omb -> e0b-high / qe0b-high / qb
    {
        int ntile = (N + Qn + B) / 16;
        wo_kernel<<<(ntile + 3) / 4, 256, 0, stream>>>(eom, hqom, omb, wswo,
                                                       e0b, qe0b, qb, N, Qn, B);
    }

    // fused conv-gather + output
    gather_out<<<(3 * B * 16 + 255) / 256, 256, 0, stream>>>(e0b, qe0b, inv,
                                                             mapid, offs2, list2,
                                                             qb, users, items, negs,
                                                             (float*)d_out, B);
}